// Round 15
// baseline (894.914 us; speedup 1.0000x reference)
//
#include <hip/hip_runtime.h>
#include <cstdint>

// ---------------- constants ----------------
#define BSZ 32
#define SEQ 512
#define DM  512
#define NH  8
#define DK  64
#define HS_ 2
#define HD_ 6
#define NL  6
#define MROWS (BSZ*SEQ)          // 16384
#define QVLD 1024                // row stride of merged q|v buffer
#define SCL 0.18033688011112043f // 0.125 * log2(e)  (exp2 domain)

typedef unsigned short bf16_t;
typedef __attribute__((ext_vector_type(4))) float f32x4;
typedef __attribute__((ext_vector_type(8))) short bf16x8;
typedef __attribute__((ext_vector_type(8))) unsigned short u16x8;

#define DEV static __device__ __forceinline__

DEV float bf2f(bf16_t b) {
  unsigned int u = ((unsigned int)b) << 16;
  float f; __builtin_memcpy(&f, &u, 4); return f;
}
DEV bf16_t f2b(float f) {  // RNE bf16 (finite inputs)
  unsigned int u; __builtin_memcpy(&u, &f, 4);
  unsigned int r = (u + 0x7fffu + ((u >> 16) & 1u)) >> 16;
  return (bf16_t)r;
}
DEV void unp2(unsigned int w, float& a, float& b) {
  unsigned int ua = w << 16, ub = w & 0xffff0000u;
  __builtin_memcpy(&a, &ua, 4); __builtin_memcpy(&b, &ub, 4);
}
DEV unsigned cvtpk(float lo, float hi) {
  unsigned r;
  asm("v_cvt_pk_bf16_f32 %0, %1, %2" : "=v"(r) : "v"(lo), "v"(hi));
  return r;
}

DEV void gload_lds16(const bf16_t* g, bf16_t* l) {
  __builtin_amdgcn_global_load_lds(
      (const __attribute__((address_space(1))) void*)g,
      (__attribute__((address_space(3))) void*)l, 16, 0, 0);
}

// scale a bf16x8 Q fragment by SCL (exp2-domain pre-scale)
DEV bf16x8 scale_q(bf16x8 v) {
  u16x8 u;
  __builtin_memcpy(&u, &v, 16);
  unsigned w[4];
#pragma unroll
  for (int e = 0; e < 4; ++e)
    w[e] = cvtpk(bf2f(u[2 * e]) * SCL, bf2f(u[2 * e + 1]) * SCL);
  bf16x8 r;
  __builtin_memcpy(&r, w, 16);
  return r;
}

// ---------------- instance-arg structs (for L0||L2 batching) ----------------
struct G8A { const bf16_t *A0, *A1, *W0, *W1; const float *b0, *b1; bf16_t* Y; };
struct GLA { const bf16_t *A, *W; const float* bias; const bf16_t* Res;
             const float *gam, *bet; bf16_t* outb; float* outf; };
struct FAA { const bf16_t* qv; const float* rdyn; bf16_t* ctx; };
struct GTA { const bf16_t* qv; const float* Wg; float* rdyn; float* fP; };

// ---------------- f32 -> bf16 converts ----------------
__global__ __launch_bounds__(256) void f2b2_kernel(
    const float* __restrict__ s0, const float* __restrict__ s1,
    bf16_t* __restrict__ d0, bf16_t* __restrict__ d1) {
  const float* s = blockIdx.y ? s1 : s0;
  bf16_t* d = blockIdx.y ? d1 : d0;
  const int i = blockIdx.x * 256 + threadIdx.x;
  float4 v = reinterpret_cast<const float4*>(s)[i];
  ushort4 o;
  o.x = f2b(v.x); o.y = f2b(v.y); o.z = f2b(v.z); o.w = f2b(v.w);
  reinterpret_cast<ushort4*>(d)[i] = o;
}

__global__ __launch_bounds__(256) void f2bw_kernel(
    const float* __restrict__ s0, const float* __restrict__ s1,
    const float* __restrict__ s2, const float* __restrict__ s3,
    const float* __restrict__ s4, bf16_t* __restrict__ dst) {
  const float* srcs[5] = {s0, s1, s2, s3, s4};
  const float* s = srcs[blockIdx.y];
  bf16_t* d = dst + (size_t)blockIdx.y * ((size_t)NL * DM * DM);
  const int i = blockIdx.x * 256 + threadIdx.x;
  float4 v = reinterpret_cast<const float4*>(s)[i];
  ushort4 o;
  o.x = f2b(v.x); o.y = f2b(v.y); o.z = f2b(v.z); o.w = f2b(v.w);
  reinterpret_cast<ushort4*>(d)[i] = o;
}

// ---------------- deep-pipelined MFMA GEMM (128x256 tile, BK=64) ----------------
// 512 thr, 8 waves (2M x 4N). 3 LDS buffers, counted vmcnt(6). Verified R10.
// blockIdx.z selects instance (L0||L2 batching).
template <int NB, int NWG, bool RELU>
__global__ __launch_bounds__(512) void gemm8(G8A ia, G8A ib, int ldy) {
  const G8A& P = blockIdx.z ? ib : ia;
  const int K = 512;
  const int lin = blockIdx.y * NB + blockIdx.x;
  const int cpx = NWG / 8;
  const int swz = (lin & 7) * cpx + (lin >> 3);
  const int bn = swz % NB, bm = swz / NB;
  const int tid = threadIdx.x, wid = tid >> 6, lane = tid & 63;
  const int wr = wid >> 2, wc = wid & 3;        // 2M x 4N waves
  const int lrow = lane & 15, grp = lane >> 4;
  const int l3 = lane >> 3, c3 = lane & 7;

  __shared__ __align__(16) bf16_t Lds[3][24576]; // per buf: A[128][64] | B[256][64]

  const bool hi = (bn * 256) >= 512;
  const bf16_t* Asel = hi ? P.A1 : P.A0;
  const bf16_t* Wsel = hi ? (P.W1 - (size_t)512 * K) : P.W0;
  const float* bsel = hi ? (P.b1 - 512) : P.b0;

  f32x4 acc[4][4];
#pragma unroll
  for (int m = 0; m < 4; ++m)
#pragma unroll
    for (int n = 0; n < 4; ++n) acc[m][n] = f32x4{0.f, 0.f, 0.f, 0.f};

  const char* LB = (const char*)Lds;

  auto stage3 = [&](int kt, int buf, int half) {
#pragma unroll
    for (int cc = 0; cc < 3; ++cc) {
      const int c = wid + (half * 3 + cc) * 8;    // 0..47
      const int colb = ((c3 ^ l3) * 8);           // pre-swizzled 16B col
      if (c < 16) {
        gload_lds16(Asel + (size_t)(bm * 128 + c * 8 + l3) * K + kt * 64 + colb,
                    &Lds[buf][c * 512]);
      } else {
        const int cb = c - 16;
        gload_lds16(Wsel + (size_t)(bn * 256 + cb * 8 + l3) * K + kt * 64 + colb,
                    &Lds[buf][8192 + cb * 512]);
      }
    }
  };
  auto rdA = [&](int buf, int rA, int ks) -> bf16x8 {
    const int off = buf * 49152 + rA * 128 + ((ks * 64 + grp * 16) ^ ((rA & 7) << 4));
    return *reinterpret_cast<const bf16x8*>(LB + off);
  };
  auto rdB = [&](int buf, int rB, int ks) -> bf16x8 {
    const int off = buf * 49152 + 16384 + rB * 128 + ((ks * 64 + grp * 16) ^ ((rB & 7) << 4));
    return *reinterpret_cast<const bf16x8*>(LB + off);
  };

  stage3(0, 0, 0); stage3(0, 0, 1);
  stage3(1, 1, 0); stage3(1, 1, 1);
  asm volatile("s_waitcnt vmcnt(6)" ::: "memory");
  __builtin_amdgcn_s_barrier();

  for (int g = 0; g < 8; ++g) {
    const int bufR = g % 3, bufW = (g + 2) % 3;
    const bool st = g < 6;
    bf16x8 bwv[4][2], afv[2][2];
#pragma unroll
    for (int n = 0; n < 4; ++n)
#pragma unroll
      for (int ks = 0; ks < 2; ++ks)
        bwv[n][ks] = rdB(bufR, wc * 64 + n * 16 + lrow, ks);
#pragma unroll
    for (int m = 0; m < 2; ++m)
#pragma unroll
      for (int ks = 0; ks < 2; ++ks)
        afv[m][ks] = rdA(bufR, wr * 64 + m * 16 + lrow, ks);
    if (st) stage3(g + 2, bufW, 0);
    __builtin_amdgcn_s_barrier();
    asm volatile("s_waitcnt lgkmcnt(0)" ::: "memory");
    __builtin_amdgcn_s_setprio(1);
#pragma unroll
    for (int ks = 0; ks < 2; ++ks)
#pragma unroll
      for (int m = 0; m < 2; ++m)
#pragma unroll
        for (int n = 0; n < 4; ++n)
          acc[m][n] = __builtin_amdgcn_mfma_f32_16x16x32_bf16(afv[m][ks], bwv[n][ks], acc[m][n], 0, 0, 0);
    __builtin_amdgcn_s_setprio(0);
    __builtin_amdgcn_s_barrier();
#pragma unroll
    for (int m = 0; m < 2; ++m)
#pragma unroll
      for (int ks = 0; ks < 2; ++ks)
        afv[m][ks] = rdA(bufR, wr * 64 + 32 + m * 16 + lrow, ks);
    if (st) stage3(g + 2, bufW, 1);
    __builtin_amdgcn_s_barrier();
    asm volatile("s_waitcnt lgkmcnt(0)" ::: "memory");
    __builtin_amdgcn_s_setprio(1);
#pragma unroll
    for (int ks = 0; ks < 2; ++ks)
#pragma unroll
      for (int m = 0; m < 2; ++m)
#pragma unroll
        for (int n = 0; n < 4; ++n)
          acc[2 + m][n] = __builtin_amdgcn_mfma_f32_16x16x32_bf16(afv[m][ks], bwv[n][ks], acc[2 + m][n], 0, 0, 0);
    __builtin_amdgcn_s_setprio(0);
    if (g < 6) {
      asm volatile("s_waitcnt vmcnt(6)" ::: "memory");
    } else if (g == 6) {
      asm volatile("s_waitcnt vmcnt(0)" ::: "memory");
    }
    __builtin_amdgcn_s_barrier();
  }

  const int r0 = bm * 128 + wr * 64 + grp * 4;
  const int c0 = bn * 256 + wc * 64 + lrow;
#pragma unroll
  for (int n = 0; n < 4; ++n) {
    const int col = c0 + n * 16;
    const float bc = bsel[col];
#pragma unroll
    for (int qm = 0; qm < 4; ++qm)
#pragma unroll
      for (int j = 0; j < 4; ++j) {
        float v = acc[qm][n][j] + bc;
        if (RELU) v = fmaxf(v, 0.f);
        P.Y[(size_t)(r0 + qm * 16 + j) * ldy + col] = f2b(v);
      }
  }
}

// ---------------- fused GEMM + bias + residual + LayerNorm (64x512 tile) ------
// Out = LN(A @ W^T + bias + Res). 512 thr, 8 waves each owning a 64-col slice.
// blockIdx.y selects instance. OUT=0: bf16 out; OUT=1: f32 out (final layer).
template <int OUT>
__global__ __launch_bounds__(512) void gemm_ln(GLA ia, GLA ib) {
  const GLA& P = blockIdx.y ? ib : ia;
  const int K = 512;
  const int bm = blockIdx.x;
  const int tid = threadIdx.x, wid = tid >> 6, lane = tid & 63;
  const int lrow = lane & 15, grp = lane >> 4;
  const int l3 = lane >> 3, c3 = lane & 7;

  __shared__ __align__(16) bf16_t Lds[2][36864];  // per buf: A[64][64] | W[512][64]
  __shared__ float red_s[64][8], red_q[64][8], stat[64][2];

  f32x4 acc[4][4];
#pragma unroll
  for (int m = 0; m < 4; ++m)
#pragma unroll
    for (int n = 0; n < 4; ++n) acc[m][n] = f32x4{0.f, 0.f, 0.f, 0.f};

  const char* LB = (const char*)Lds;

  auto stage = [&](int kt, int buf) {
#pragma unroll
    for (int k = 0; k < 9; ++k) {
      const int c = wid + k * 8;           // 0..71
      const int colb = (c3 ^ l3) * 8;      // pre-swizzled 16B col
      if (c < 8) {                         // A chunk: rows c*8..c*8+7
        gload_lds16(P.A + (size_t)(bm * 64 + c * 8 + l3) * K + kt * 64 + colb,
                    &Lds[buf][c * 512]);
      } else {                             // W chunk
        const int cb = c - 8;
        gload_lds16(P.W + (size_t)(cb * 8 + l3) * K + kt * 64 + colb,
                    &Lds[buf][4096 + cb * 512]);
      }
    }
  };
  auto rdA = [&](int buf, int r, int ks) -> bf16x8 {
    const int off = buf * 73728 + r * 128 + ((ks * 64 + grp * 16) ^ ((r & 7) << 4));
    return *reinterpret_cast<const bf16x8*>(LB + off);
  };
  auto rdW = [&](int buf, int r, int ks) -> bf16x8 {
    const int off = buf * 73728 + 8192 + r * 128 + ((ks * 64 + grp * 16) ^ ((r & 7) << 4));
    return *reinterpret_cast<const bf16x8*>(LB + off);
  };

  stage(0, 0);
  __syncthreads();
  for (int g = 0; g < 8; ++g) {
    const int bufR = g & 1;
    if (g < 7) stage(g + 1, bufR ^ 1);
    bf16x8 af[4][2], wf[4][2];
#pragma unroll
    for (int m = 0; m < 4; ++m)
#pragma unroll
      for (int ks = 0; ks < 2; ++ks)
        af[m][ks] = rdA(bufR, m * 16 + lrow, ks);
#pragma unroll
    for (int n = 0; n < 4; ++n)
#pragma unroll
      for (int ks = 0; ks < 2; ++ks)
        wf[n][ks] = rdW(bufR, wid * 64 + n * 16 + lrow, ks);
    __builtin_amdgcn_s_setprio(1);
#pragma unroll
    for (int ks = 0; ks < 2; ++ks)
#pragma unroll
      for (int m = 0; m < 4; ++m)
#pragma unroll
        for (int n = 0; n < 4; ++n)
          acc[m][n] = __builtin_amdgcn_mfma_f32_16x16x32_bf16(af[m][ks], wf[n][ks], acc[m][n], 0, 0, 0);
    __builtin_amdgcn_s_setprio(0);
    __syncthreads();   // drains vmcnt (stage g+1 resident) + lgkm
  }

  // ---- epilogue: z = acc + bias + res; rowwise LN; store ----
  const int cbase = wid * 64;
  float bias_n[4], gam_n[4], bet_n[4];
#pragma unroll
  for (int n = 0; n < 4; ++n) {
    bias_n[n] = P.bias[cbase + n * 16 + lrow];
    gam_n[n]  = P.gam[cbase + n * 16 + lrow];
    bet_n[n]  = P.bet[cbase + n * 16 + lrow];
  }
  const size_t rowg0 = (size_t)bm * 64;
  float ps[4][4], pq[4][4];
#pragma unroll
  for (int m = 0; m < 4; ++m)
#pragma unroll
    for (int j = 0; j < 4; ++j) {
      const int r = m * 16 + grp * 4 + j;
      float s = 0.f, q = 0.f;
#pragma unroll
      for (int n = 0; n < 4; ++n) {
        float z = acc[m][n][j] + bias_n[n] +
                  bf2f(P.Res[(rowg0 + r) * DM + cbase + n * 16 + lrow]);
        acc[m][n][j] = z;
        s += z; q += z * z;
      }
      ps[m][j] = s; pq[m][j] = q;
    }
#pragma unroll
  for (int m = 0; m < 4; ++m)
#pragma unroll
    for (int j = 0; j < 4; ++j)
#pragma unroll
      for (int off = 1; off <= 8; off <<= 1) {
        ps[m][j] += __shfl_xor(ps[m][j], off);
        pq[m][j] += __shfl_xor(pq[m][j], off);
      }
  if (lrow == 0) {
#pragma unroll
    for (int m = 0; m < 4; ++m)
#pragma unroll
      for (int j = 0; j < 4; ++j) {
        const int r = m * 16 + grp * 4 + j;
        red_s[r][wid] = ps[m][j];
        red_q[r][wid] = pq[m][j];
      }
  }
  __syncthreads();
  if (tid < 64) {
    float s = 0.f, q = 0.f;
#pragma unroll
    for (int w = 0; w < 8; ++w) { s += red_s[tid][w]; q += red_q[tid][w]; }
    const float mean = s * (1.f / 512.f);
    const float var = q * (1.f / 512.f) - mean * mean;
    stat[tid][0] = mean;
    stat[tid][1] = rsqrtf(var + 1e-5f);
  }
  __syncthreads();
#pragma unroll
  for (int m = 0; m < 4; ++m)
#pragma unroll
    for (int j = 0; j < 4; ++j) {
      const int r = m * 16 + grp * 4 + j;
      const float mean = stat[r][0], rstd = stat[r][1];
#pragma unroll
      for (int n = 0; n < 4; ++n) {
        const float o = (acc[m][n][j] - mean) * rstd * gam_n[n] + bet_n[n];
        const size_t off = (rowg0 + r) * DM + cbase + n * 16 + lrow;
        if (OUT == 0) P.outb[off] = f2b(o);
        else P.outf[off] = o;
      }
    }
}

// ---------------- gating: softmax(q @ Wg^T), top-4-of-6, fused routing ----------------
// blockIdx.y selects instance.
__global__ __launch_bounds__(256) void gates_kernel(GTA ia, GTA ib) {
  const GTA& P = blockIdx.y ? ib : ia;
  __shared__ float wg_s[HD_ * DM];
  __shared__ float blk[4][18];
  const int tid = threadIdx.x, wid = tid >> 6, lane = tid & 63;
  for (int i = tid; i < HD_ * DM / 4; i += 256)
    reinterpret_cast<float4*>(wg_s)[i] = reinterpret_cast<const float4*>(P.Wg)[i];
  __syncthreads();
  const int bb = blockIdx.x >> 4;
  const int t0 = (blockIdx.x & 15) * 32 + wid * 8;
  float fs[6] = {0, 0, 0, 0, 0, 0}, ps[6] = {0, 0, 0, 0, 0, 0}, rs[6] = {0, 0, 0, 0, 0, 0};
  for (int it = 0; it < 8; ++it) {
    const int tok = bb * SEQ + t0 + it;
    uint4 u = reinterpret_cast<const uint4*>(P.qv + (size_t)tok * QVLD)[lane];
    float x[8];
    unp2(u.x, x[0], x[1]); unp2(u.y, x[2], x[3]);
    unp2(u.z, x[4], x[5]); unp2(u.w, x[6], x[7]);
    float g[6];
#pragma unroll
    for (int j = 0; j < 6; ++j) {
      float p = 0.f;
#pragma unroll
      for (int e = 0; e < 8; ++e) p = fmaf(x[e], wg_s[j * DM + lane * 8 + e], p);
#pragma unroll
      for (int off = 32; off; off >>= 1) p += __shfl_xor(p, off);
      g[j] = p;
    }
    float mx = g[0];
#pragma unroll
    for (int j = 1; j < 6; ++j) mx = fmaxf(mx, g[j]);
    float se = 0.f;
#pragma unroll
    for (int j = 0; j < 6; ++j) { g[j] = __expf(g[j] - mx); se += g[j]; }
    float inv = 1.f / se;
#pragma unroll
    for (int j = 0; j < 6; ++j) g[j] *= inv;
    int d1 = 0;
#pragma unroll
    for (int j = 1; j < 6; ++j)
      if (g[j] < g[d1] || (g[j] == g[d1] && j > d1)) d1 = j;
    int d2 = (d1 == 0) ? 1 : 0;
#pragma unroll
    for (int j = 0; j < 6; ++j) {
      if (j == d1) continue;
      if (g[j] < g[d2] || (g[j] == g[d2] && j > d2)) d2 = j;
    }
#pragma unroll
    for (int j = 0; j < 6; ++j) {
      const bool drop = (j == d1) || (j == d2);
      fs[j] += drop ? 0.f : 1.f;
      ps[j] += g[j];
      rs[j] += drop ? 0.f : g[j];
    }
  }
  if (lane == 0) {
#pragma unroll
    for (int j = 0; j < 6; ++j) {
      blk[wid][j] = fs[j]; blk[wid][6 + j] = ps[j]; blk[wid][12 + j] = rs[j];
    }
  }
  __syncthreads();
  if (tid < 18) {
    float s = blk[0][tid] + blk[1][tid] + blk[2][tid] + blk[3][tid];
    if (tid < 12) atomicAdd(&P.fP[tid], s);
    else atomicAdd(&P.rdyn[bb * 6 + (tid - 12)], s * (1.f / 512.f));
  }
}

// ---------------- fused flash attention (MFMA, row0 fused) --------------------
// grid (bh=256, qt=4, inst). blockIdx.z selects instance.
__global__ __launch_bounds__(256, 2) void fattn_kernel(FAA ia, FAA ib, int strict) {
  const FAA& P = blockIdx.z ? ib : ia;
  const int bh = blockIdx.x, qt = blockIdx.y;
  const int b = bh >> 3, h = bh & 7;
  const int tid = threadIdx.x, wid = tid >> 6, lane = tid & 63;
  const int c0 = lane & 15, grp = lane >> 4;
  const int l3 = lane >> 3, c3 = lane & 7;
  const int kidx = lane & 31, dhalf = lane >> 5;

  __shared__ __align__(16) bf16_t Ks[64 * 64];
  __shared__ __align__(16) bf16_t Vt[64 * 72];
  __shared__ __align__(16) bf16_t Ps[4][32 * 64];
  __shared__ float csum[64];

  const bf16_t* qp = P.qv;
  const bf16_t* vp = P.qv + 512;
  const float factor = (h < HS_) ? 1.f : P.rdyn[b * 6 + (h - HS_)];

  const int qbase = qt * 128 + wid * 32;

  bf16x8 qf[2][2];
#pragma unroll
  for (int nt = 0; nt < 2; ++nt)
#pragma unroll
    for (int ks = 0; ks < 2; ++ks)
      qf[nt][ks] = scale_q(*reinterpret_cast<const bf16x8*>(
          qp + ((size_t)(b * SEQ + qbase + nt * 16 + c0)) * QVLD + h * DK + ks * 32 + grp * 8));

  f32x4 acc[2][4];
#pragma unroll
  for (int m = 0; m < 2; ++m)
#pragma unroll
    for (int d = 0; d < 4; ++d) acc[m][d] = f32x4{0.f, 0.f, 0.f, 0.f};
  float mreg[2] = {-3e38f, -3e38f};
  float lreg[2] = {0.f, 0.f};
  float cs[8] = {0, 0, 0, 0, 0, 0, 0, 0};

  const int lastk = (qbase + 31 - strict) >> 6;
  const int ktmax = 2 * qt + 1;

  for (int kt = 0; kt <= ktmax; ++kt) {
#pragma unroll
    for (int i = 0; i < 2; ++i) {
      int row = i * 32 + wid * 8 + l3;
      int blk = c3 ^ l3;
      gload_lds16(qp + ((size_t)(b * SEQ + kt * 64 + row)) * QVLD + h * DK + blk * 8,
                  Ks + (i * 32 + wid * 8) * 64);
    }
#pragma unroll
    for (int j = 0; j < 2; ++j) {
      const int d0 = (wid * 2 + j) * 8 + dhalf * 4;
      const bf16_t* src = vp + ((size_t)(b * SEQ + kt * 64 + 2 * kidx)) * QVLD + h * DK + d0;
      ushort4 lo = *reinterpret_cast<const ushort4*>(src);
      ushort4 hv = *reinterpret_cast<const ushort4*>(src + QVLD);
      *reinterpret_cast<unsigned*>(&Vt[(d0 + 0) * 72 + 2 * kidx]) = (unsigned)lo.x | ((unsigned)hv.x << 16);
      *reinterpret_cast<unsigned*>(&Vt[(d0 + 1) * 72 + 2 * kidx]) = (unsigned)lo.y | ((unsigned)hv.y << 16);
      *reinterpret_cast<unsigned*>(&Vt[(d0 + 2) * 72 + 2 * kidx]) = (unsigned)lo.z | ((unsigned)hv.z << 16);
      *reinterpret_cast<unsigned*>(&Vt[(d0 + 3) * 72 + 2 * kidx]) = (unsigned)lo.w | ((unsigned)hv.w << 16);
      if (qt == 3) {
        cs[j * 4 + 0] += bf2f(lo.x) + bf2f(hv.x);
        cs[j * 4 + 1] += bf2f(lo.y) + bf2f(hv.y);
        cs[j * 4 + 2] += bf2f(lo.z) + bf2f(hv.z);
        cs[j * 4 + 3] += bf2f(lo.w) + bf2f(hv.w);
      }
    }
    __syncthreads();

    if (kt <= lastk) {
      const char* KsB = (const char*)Ks;
      bf16x8 kf[4][2];
#pragma unroll
      for (int mt = 0; mt < 4; ++mt)
#pragma unroll
        for (int ks = 0; ks < 2; ++ks)
          kf[mt][ks] = *reinterpret_cast<const bf16x8*>(
              KsB + (mt * 16 + c0) * 128 + 16 * ((4 * ks + grp) ^ (c0 & 7)));
      f32x4 s[4][2];
#pragma unroll
      for (int mt = 0; mt < 4; ++mt)
#pragma unroll
        for (int nt = 0; nt < 2; ++nt) s[mt][nt] = f32x4{0.f, 0.f, 0.f, 0.f};
      __builtin_amdgcn_s_setprio(1);
#pragma unroll
      for (int mt = 0; mt < 4; ++mt)
#pragma unroll
        for (int nt = 0; nt < 2; ++nt)
#pragma unroll
          for (int ks = 0; ks < 2; ++ks)
            s[mt][nt] = __builtin_amdgcn_mfma_f32_16x16x32_bf16(
                kf[mt][ks], qf[nt][ks], s[mt][nt], 0, 0, 0);
      __builtin_amdgcn_s_setprio(0);

      const bool masked = (kt == lastk);
      if (masked) {
#pragma unroll
        for (int nt = 0; nt < 2; ++nt) {
          const int q = qbase + nt * 16 + c0;
#pragma unroll
          for (int mt = 0; mt < 4; ++mt)
#pragma unroll
            for (int j = 0; j < 4; ++j) {
              int k = kt * 64 + mt * 16 + grp * 4 + j;
              if (k + strict > q) s[mt][nt][j] = -1e30f;
            }
        }
      }
      float mx[2];
#pragma unroll
      for (int nt = 0; nt < 2; ++nt) {
        float a = fmaxf(s[0][nt][0], s[0][nt][1]);
        a = fmaxf(fmaxf(a, s[0][nt][2]), s[0][nt][3]);
        float bm_ = fmaxf(s[1][nt][0], s[1][nt][1]);
        bm_ = fmaxf(fmaxf(bm_, s[1][nt][2]), s[1][nt][3]);
        float c = fmaxf(s[2][nt][0], s[2][nt][1]);
        c = fmaxf(fmaxf(c, s[2][nt][2]), s[2][nt][3]);
        float d = fmaxf(s[3][nt][0], s[3][nt][1]);
        d = fmaxf(fmaxf(d, s[3][nt][2]), s[3][nt][3]);
        float m_ = fmaxf(fmaxf(a, bm_), fmaxf(c, d));
        m_ = fmaxf(m_, __shfl_xor(m_, 16));
        m_ = fmaxf(m_, __shfl_xor(m_, 32));
        mx[nt] = m_;
      }
      const bool defer = __all((mx[0] - mreg[0] <= 8.f) && (mx[1] - mreg[1] <= 8.f));
      float sc[2];
#pragma unroll
      for (int nt = 0; nt < 2; ++nt) {
        const float mnew = defer ? mreg[nt] : fmaxf(mreg[nt], mx[nt]);
        float ts = 0.f;
#pragma unroll
        for (int mt = 0; mt < 4; ++mt)
#pragma unroll
          for (int j = 0; j < 4; ++j) {
            float pp = exp2f(s[mt][nt][j] - mnew);
            s[mt][nt][j] = pp; ts += pp;
          }
        ts += __shfl_xor(ts, 16);
        ts += __shfl_xor(ts, 32);
        if (defer) {
          lreg[nt] += ts;
        } else {
          sc[nt] = exp2f(mreg[nt] - mnew);
          lreg[nt] = lreg[nt] * sc[nt] + ts;
          mreg[nt] = mnew;
        }
      }
      char* PsB = (char*)(&Ps[wid][0]);
#pragma unroll
      for (int nt = 0; nt < 2; ++nt)
#pragma unroll
        for (int mt = 0; mt < 4; ++mt) {
          uint2 w;
          w.x = cvtpk(s[mt][nt][0], s[mt][nt][1]);
          w.y = cvtpk(s[mt][nt][2], s[mt][nt][3]);
          int row = nt * 16 + c0;
          int off = (row * 128 + mt * 32 + grp * 8) ^ ((c0 & 7) << 4);
          *reinterpret_cast<uint2*>(PsB + off) = w;
        }
      if (!defer) {
#pragma unroll
        for (int mtq = 0; mtq < 2; ++mtq) {
          f32x4 sv;
#pragma unroll
          for (int j = 0; j < 4; ++j) sv[j] = __shfl(sc[mtq], grp * 4 + j);
#pragma unroll
          for (int dt = 0; dt < 4; ++dt) acc[mtq][dt] *= sv;
        }
      }
      bf16x8 pf[2][2], vf2[4][2];
#pragma unroll
      for (int mtq = 0; mtq < 2; ++mtq)
#pragma unroll
        for (int ks = 0; ks < 2; ++ks)
          pf[mtq][ks] = *reinterpret_cast<const bf16x8*>(
              PsB + (mtq * 16 + c0) * 128 + 16 * ((4 * ks + grp) ^ (c0 & 7)));
#pragma unroll
      for (int dt = 0; dt < 4; ++dt)
#pragma unroll
        for (int ks = 0; ks < 2; ++ks)
          vf2[dt][ks] = *reinterpret_cast<const bf16x8*>(
              (const char*)Vt + (dt * 16 + c0) * 144 + ks * 64 + grp * 16);
      __builtin_amdgcn_s_setprio(1);
#pragma unroll
      for (int mtq = 0; mtq < 2; ++mtq)
#pragma unroll
        for (int dt = 0; dt < 4; ++dt)
#pragma unroll
          for (int ks = 0; ks < 2; ++ks)
            acc[mtq][dt] = __builtin_amdgcn_mfma_f32_16x16x32_bf16(
                pf[mtq][ks], vf2[dt][ks], acc[mtq][dt], 0, 0, 0);
      __builtin_amdgcn_s_setprio(0);
    }
    __syncthreads();
  }

  if (qt == 3) {
#pragma unroll
    for (int e = 0; e < 8; ++e)
#pragma unroll
      for (int off = 1; off <= 16; off <<= 1) cs[e] += __shfl_xor(cs[e], off);
    if ((lane & 31) == 0) {
#pragma unroll
      for (int e = 0; e < 8; ++e)
        csum[(wid * 2 + (e >> 2)) * 8 + dhalf * 4 + (e & 3)] = cs[e];
    }
    __syncthreads();
    if (tid < 64)
      P.ctx[((size_t)(b * SEQ)) * DM + h * DK + tid] = f2b(csum[tid] * (1.f / 512.f) * factor);
  }

#pragma unroll
  for (int mtq = 0; mtq < 2; ++mtq) {
    const float inv = factor / lreg[mtq];
    f32x4 iv;
#pragma unroll
    for (int j = 0; j < 4; ++j) iv[j] = __shfl(inv, grp * 4 + j);
#pragma unroll
    for (int j = 0; j < 4; ++j) {
      const int q = qbase + mtq * 16 + grp * 4 + j;
      if (q == 0) continue;
#pragma unroll
      for (int dt = 0; dt < 4; ++dt)
        P.ctx[((size_t)(b * SEQ + q)) * DM + h * DK + dt * 16 + c0] =
            f2b(acc[mtq][dt][j] * iv[j]);
    }
  }
}

// ---------------- balance ----------------
__global__ void balance_kernel(const float* __restrict__ fP, float* __restrict__ out) {
  if (threadIdx.x == 0 && blockIdx.x == 0) {
    float fs = 0.f, pssum = 0.f, P[6];
    for (int j = 0; j < 6; ++j) {
      fs += fP[j];
      P[j] = fP[6 + j] * (1.f / (float)MROWS);
      pssum += P[j];
    }
    float bal = 0.f;
    for (int j = 0; j < 6; ++j)
      bal += (fP[j] / (fs + 1e-5f)) * (P[j] / (pssum + 1e-5f));
    out[0] = bal;
  }
}

// ---------------- host ----------------
extern "C" void kernel_launch(void* const* d_in, const int* in_sizes, int n_in,
                              void* d_out, int out_size, void* d_ws, size_t ws_size,
                              hipStream_t stream) {
  (void)in_sizes; (void)n_in; (void)out_size; (void)ws_size;
  const float* q_embed  = (const float*)d_in[0];
  const float* qa_embed = (const float*)d_in[1];
  const float* Wq  = (const float*)d_in[2];
  const float* bq  = (const float*)d_in[3];
  const float* Wv  = (const float*)d_in[4];
  const float* bv  = (const float*)d_in[5];
  const float* Wg  = (const float*)d_in[6];
  const float* Wo  = (const float*)d_in[7];
  const float* bo  = (const float*)d_in[8];
  const float* ln1g = (const float*)d_in[9];
  const float* ln1b = (const float*)d_in[10];
  const float* W1  = (const float*)d_in[11];
  const float* b1  = (const float*)d_in[12];
  const float* W2  = (const float*)d_in[13];
  const float* b2  = (const float*)d_in[14];
  const float* ln2g = (const float*)d_in[15];
  const float* ln2b = (const float*)d_in[16];

  char* p = (char*)d_ws;
  auto alloc = [&](size_t bytes) -> char* {
    char* r = p; p += (bytes + 255) & ~(size_t)255; return r;
  };
  const size_t WDE = (size_t)NL * DM * DM;   // stacked weight elems (per tensor)
  const size_t AE  = (size_t)MROWS * DM;     // activation elems
  bf16_t* wall_b = (bf16_t*)alloc(5 * WDE * 2);   // wq|wv|wo|w1|w2 contiguous
  bf16_t* wq_b = wall_b;
  bf16_t* wv_b = wall_b + WDE;
  bf16_t* wo_b = wall_b + 2 * WDE;
  bf16_t* w1_b = wall_b + 3 * WDE;
  bf16_t* w2_b = wall_b + 4 * WDE;
  bf16_t* y_b   = (bf16_t*)alloc(AE * 2);
  bf16_t* x_b   = (bf16_t*)alloc(AE * 2);
  bf16_t* qv_b  = (bf16_t*)alloc((size_t)MROWS * QVLD * 2);   // q|v merged (inst 0)
  bf16_t* qv2_b = (bf16_t*)alloc((size_t)MROWS * QVLD * 2);   // inst 1
  bf16_t* ctx_b  = (bf16_t*)alloc(AE * 2);
  bf16_t* ctx2_b = (bf16_t*)alloc(AE * 2);
  bf16_t* x1_b   = (bf16_t*)alloc(AE * 2);
  bf16_t* x12_b  = (bf16_t*)alloc(AE * 2);
  bf16_t* ffn1_b  = (bf16_t*)alloc(AE * 2);
  bf16_t* ffn12_b = (bf16_t*)alloc(AE * 2);
  float* stats = (float*)alloc(NL * (12 + BSZ * 6) * 4);  // fP[NL][12] | rdyn[NL][32][6]
  float* fPbase = stats;
  float* rdynbase = stats + NL * 12;

  hipMemsetAsync(stats, 0, NL * (12 + BSZ * 6) * 4, stream);

  f2bw_kernel<<<dim3((unsigned)(WDE / 4 / 256), 5), 256, 0, stream>>>(
      Wq, Wv, Wo, W1, W2, wall_b);
  f2b2_kernel<<<dim3((unsigned)(AE / 4 / 256), 2), 256, 0, stream>>>(
      qa_embed, q_embed, y_b, x_b);

  const size_t DD = (size_t)DM * DM;
  float* outx = (float*)d_out;

  struct Bufs { bf16_t *qv, *ctx, *x1, *ffn1; };
  Bufs B0{qv_b, ctx_b, x1_b, ffn1_b}, B1{qv2_b, ctx2_b, x12_b, ffn12_b};

  // one "unit": nb instances (1 or 2). For nb==1 duplicate instance a.
  auto unit = [&](int nb, int i0, int i1, bf16_t* res0, const bf16_t* xv0,
                  bf16_t* res1, const bf16_t* xv1, int strict, bool last) {
    G8A qa{res0, xv0, wq_b + i0 * DD, wv_b + i0 * DD, bq + i0 * DM, bv + i0 * DM, B0.qv};
    G8A qb{res1, xv1, wq_b + i1 * DD, wv_b + i1 * DD, bq + i1 * DM, bv + i1 * DM, B1.qv};
    gemm8<4, 512, false><<<dim3(4, 128, nb), 512, 0, stream>>>(qa, qb, QVLD);

    GTA ga{B0.qv, Wg + (size_t)i0 * HD_ * DM, rdynbase + i0 * (BSZ * 6), fPbase + i0 * 12};
    GTA gb{B1.qv, Wg + (size_t)i1 * HD_ * DM, rdynbase + i1 * (BSZ * 6), fPbase + i1 * 12};
    gates_kernel<<<dim3(MROWS / 32, nb), 256, 0, stream>>>(ga, gb);

    FAA fa{B0.qv, rdynbase + i0 * (BSZ * 6), B0.ctx};
    FAA fb{B1.qv, rdynbase + i1 * (BSZ * 6), B1.ctx};
    fattn_kernel<<<dim3(256, 4, nb), 256, 0, stream>>>(fa, fb, strict);

    GLA la{B0.ctx, wo_b + i0 * DD, bo + i0 * DM, res0, ln1g + i0 * DM, ln1b + i0 * DM, B0.x1, nullptr};
    GLA lb{B1.ctx, wo_b + i1 * DD, bo + i1 * DM, res1, ln1g + i1 * DM, ln1b + i1 * DM, B1.x1, nullptr};
    gemm_ln<0><<<dim3(256, nb), 512, 0, stream>>>(la, lb);

    G8A f1a{B0.x1, B0.x1, w1_b + i0 * DD, w1_b + i0 * DD, b1 + i0 * DM, b1 + i0 * DM, B0.ffn1};
    G8A f1b{B1.x1, B1.x1, w1_b + i1 * DD, w1_b + i1 * DD, b1 + i1 * DM, b1 + i1 * DM, B1.ffn1};
    gemm8<2, 256, true><<<dim3(2, 128, nb), 512, 0, stream>>>(f1a, f1b, DM);

    GLA m0{B0.ffn1, w2_b + i0 * DD, b2 + i0 * DM, B0.x1, ln2g + i0 * DM, ln2b + i0 * DM, res0, nullptr};
    GLA m1{B1.ffn1, w2_b + i1 * DD, b2 + i1 * DM, B1.x1, ln2g + i1 * DM, ln2b + i1 * DM, res1, nullptr};
    if (last) {
      m0.outb = nullptr; m0.outf = outx;
      gemm_ln<1><<<dim3(256, nb), 512, 0, stream>>>(m0, m1);
    } else {
      gemm_ln<0><<<dim3(256, nb), 512, 0, stream>>>(m0, m1);
    }
  };

  // {L0 || L2} -> L1 -> L3 -> L4 -> L5
  unit(2, 0, 2, y_b, y_b, x_b, x_b, 0, false);     // L0 (y self) || L2 (x self)
  unit(1, 1, 1, y_b, y_b, y_b, y_b, 0, false);     // L1
  unit(1, 3, 3, x_b, y_b, x_b, y_b, 1, false);     // L3 (cross, strict)
  unit(1, 4, 4, x_b, x_b, x_b, x_b, 0, false);     // L4
  unit(1, 5, 5, x_b, y_b, x_b, y_b, 1, true);      // L5 (cross, strict, final)

  balance_kernel<<<1, 64, 0, stream>>>(fPbase + 5 * 12, outx + (size_t)MROWS * DM);
}

// Round 16
// 886.439 us; speedup vs baseline: 1.0096x; 1.0096x over previous
//
#include <hip/hip_runtime.h>
#include <cstdint>

// ---------------- constants ----------------
#define BSZ 32
#define SEQ 512
#define DM  512
#define NH  8
#define DK  64
#define HS_ 2
#define HD_ 6
#define NL  6
#define MROWS (BSZ*SEQ)          // 16384
#define QVLD 1024                // row stride of merged q|v buffer
#define SCL 0.18033688011112043f // 0.125 * log2(e)  (exp2 domain)

typedef unsigned short bf16_t;
typedef __attribute__((ext_vector_type(4))) float f32x4;
typedef __attribute__((ext_vector_type(8))) short bf16x8;
typedef __attribute__((ext_vector_type(8))) unsigned short u16x8;

#define DEV static __device__ __forceinline__

DEV float bf2f(bf16_t b) {
  unsigned int u = ((unsigned int)b) << 16;
  float f; __builtin_memcpy(&f, &u, 4); return f;
}
DEV bf16_t f2b(float f) {  // RNE bf16 (finite inputs)
  unsigned int u; __builtin_memcpy(&u, &f, 4);
  unsigned int r = (u + 0x7fffu + ((u >> 16) & 1u)) >> 16;
  return (bf16_t)r;
}
DEV void unp2(unsigned int w, float& a, float& b) {
  unsigned int ua = w << 16, ub = w & 0xffff0000u;
  __builtin_memcpy(&a, &ua, 4); __builtin_memcpy(&b, &ub, 4);
}
DEV unsigned cvtpk(float lo, float hi) {
  unsigned r;
  asm("v_cvt_pk_bf16_f32 %0, %1, %2" : "=v"(r) : "v"(lo), "v"(hi));
  return r;
}

DEV void gload_lds16(const bf16_t* g, bf16_t* l) {
  __builtin_amdgcn_global_load_lds(
      (const __attribute__((address_space(1))) void*)g,
      (__attribute__((address_space(3))) void*)l, 16, 0, 0);
}

// scale a bf16x8 Q fragment by SCL (exp2-domain pre-scale)
DEV bf16x8 scale_q(bf16x8 v) {
  u16x8 u;
  __builtin_memcpy(&u, &v, 16);
  unsigned w[4];
#pragma unroll
  for (int e = 0; e < 4; ++e)
    w[e] = cvtpk(bf2f(u[2 * e]) * SCL, bf2f(u[2 * e + 1]) * SCL);
  bf16x8 r;
  __builtin_memcpy(&r, w, 16);
  return r;
}

// ---------------- f32 -> bf16 converts ----------------
__global__ __launch_bounds__(256) void f2b2_kernel(
    const float* __restrict__ s0, const float* __restrict__ s1,
    bf16_t* __restrict__ d0, bf16_t* __restrict__ d1) {
  const float* s = blockIdx.y ? s1 : s0;
  bf16_t* d = blockIdx.y ? d1 : d0;
  const int i = blockIdx.x * 256 + threadIdx.x;
  float4 v = reinterpret_cast<const float4*>(s)[i];
  ushort4 o;
  o.x = f2b(v.x); o.y = f2b(v.y); o.z = f2b(v.z); o.w = f2b(v.w);
  reinterpret_cast<ushort4*>(d)[i] = o;
}

__global__ __launch_bounds__(256) void f2bw_kernel(
    const float* __restrict__ s0, const float* __restrict__ s1,
    const float* __restrict__ s2, const float* __restrict__ s3,
    const float* __restrict__ s4, bf16_t* __restrict__ dst) {
  const float* srcs[5] = {s0, s1, s2, s3, s4};
  const float* s = srcs[blockIdx.y];
  bf16_t* d = dst + (size_t)blockIdx.y * ((size_t)NL * DM * DM);
  const int i = blockIdx.x * 256 + threadIdx.x;
  float4 v = reinterpret_cast<const float4*>(s)[i];
  ushort4 o;
  o.x = f2b(v.x); o.y = f2b(v.y); o.z = f2b(v.z); o.w = f2b(v.w);
  reinterpret_cast<ushort4*>(d)[i] = o;
}

// ---------------- deep-pipelined MFMA GEMM (128x256 tile, BK=64) ----------------
// 512 thr, 8 waves (2M x 4N). 3 LDS buffers, counted vmcnt(6). Verified R10.
template <int NB, int NWG, bool RELU>
__global__ __launch_bounds__(512) void gemm8(
    const bf16_t* __restrict__ A0, const bf16_t* __restrict__ A1,
    const bf16_t* __restrict__ W0, const bf16_t* __restrict__ W1,
    const float* __restrict__ b0, const float* __restrict__ b1,
    bf16_t* __restrict__ Yb, int ldy) {
  const int K = 512;
  const int lin = blockIdx.y * NB + blockIdx.x;
  const int cpx = NWG / 8;
  const int swz = (lin & 7) * cpx + (lin >> 3);
  const int bn = swz % NB, bm = swz / NB;
  const int tid = threadIdx.x, wid = tid >> 6, lane = tid & 63;
  const int wr = wid >> 2, wc = wid & 3;        // 2M x 4N waves
  const int lrow = lane & 15, grp = lane >> 4;
  const int l3 = lane >> 3, c3 = lane & 7;

  __shared__ __align__(16) bf16_t Lds[3][24576]; // per buf: A[128][64] | B[256][64]

  const bool hi = (bn * 256) >= 512;
  const bf16_t* Asel = hi ? A1 : A0;
  const bf16_t* Wsel = hi ? (W1 - (size_t)512 * K) : W0;
  const float* bsel = hi ? (b1 - 512) : b0;

  f32x4 acc[4][4];
#pragma unroll
  for (int m = 0; m < 4; ++m)
#pragma unroll
    for (int n = 0; n < 4; ++n) acc[m][n] = f32x4{0.f, 0.f, 0.f, 0.f};

  const char* LB = (const char*)Lds;

  auto stage3 = [&](int kt, int buf, int half) {
#pragma unroll
    for (int cc = 0; cc < 3; ++cc) {
      const int c = wid + (half * 3 + cc) * 8;    // 0..47
      const int colb = ((c3 ^ l3) * 8);           // pre-swizzled 16B col
      if (c < 16) {
        gload_lds16(Asel + (size_t)(bm * 128 + c * 8 + l3) * K + kt * 64 + colb,
                    &Lds[buf][c * 512]);
      } else {
        const int cb = c - 16;
        gload_lds16(Wsel + (size_t)(bn * 256 + cb * 8 + l3) * K + kt * 64 + colb,
                    &Lds[buf][8192 + cb * 512]);
      }
    }
  };
  auto rdA = [&](int buf, int rA, int ks) -> bf16x8 {
    const int off = buf * 49152 + rA * 128 + ((ks * 64 + grp * 16) ^ ((rA & 7) << 4));
    return *reinterpret_cast<const bf16x8*>(LB + off);
  };
  auto rdB = [&](int buf, int rB, int ks) -> bf16x8 {
    const int off = buf * 49152 + 16384 + rB * 128 + ((ks * 64 + grp * 16) ^ ((rB & 7) << 4));
    return *reinterpret_cast<const bf16x8*>(LB + off);
  };

  stage3(0, 0, 0); stage3(0, 0, 1);
  stage3(1, 1, 0); stage3(1, 1, 1);
  asm volatile("s_waitcnt vmcnt(6)" ::: "memory");
  __builtin_amdgcn_s_barrier();

  for (int g = 0; g < 8; ++g) {
    const int bufR = g % 3, bufW = (g + 2) % 3;
    const bool st = g < 6;
    bf16x8 bwv[4][2], afv[2][2];
#pragma unroll
    for (int n = 0; n < 4; ++n)
#pragma unroll
      for (int ks = 0; ks < 2; ++ks)
        bwv[n][ks] = rdB(bufR, wc * 64 + n * 16 + lrow, ks);
#pragma unroll
    for (int m = 0; m < 2; ++m)
#pragma unroll
      for (int ks = 0; ks < 2; ++ks)
        afv[m][ks] = rdA(bufR, wr * 64 + m * 16 + lrow, ks);
    if (st) stage3(g + 2, bufW, 0);
    __builtin_amdgcn_s_barrier();
    asm volatile("s_waitcnt lgkmcnt(0)" ::: "memory");
    __builtin_amdgcn_s_setprio(1);
#pragma unroll
    for (int ks = 0; ks < 2; ++ks)
#pragma unroll
      for (int m = 0; m < 2; ++m)
#pragma unroll
        for (int n = 0; n < 4; ++n)
          acc[m][n] = __builtin_amdgcn_mfma_f32_16x16x32_bf16(afv[m][ks], bwv[n][ks], acc[m][n], 0, 0, 0);
    __builtin_amdgcn_s_setprio(0);
    __builtin_amdgcn_s_barrier();
#pragma unroll
    for (int m = 0; m < 2; ++m)
#pragma unroll
      for (int ks = 0; ks < 2; ++ks)
        afv[m][ks] = rdA(bufR, wr * 64 + 32 + m * 16 + lrow, ks);
    if (st) stage3(g + 2, bufW, 1);
    __builtin_amdgcn_s_barrier();
    asm volatile("s_waitcnt lgkmcnt(0)" ::: "memory");
    __builtin_amdgcn_s_setprio(1);
#pragma unroll
    for (int ks = 0; ks < 2; ++ks)
#pragma unroll
      for (int m = 0; m < 2; ++m)
#pragma unroll
        for (int n = 0; n < 4; ++n)
          acc[2 + m][n] = __builtin_amdgcn_mfma_f32_16x16x32_bf16(afv[m][ks], bwv[n][ks], acc[2 + m][n], 0, 0, 0);
    __builtin_amdgcn_s_setprio(0);
    if (g < 6) {
      asm volatile("s_waitcnt vmcnt(6)" ::: "memory");
    } else if (g == 6) {
      asm volatile("s_waitcnt vmcnt(0)" ::: "memory");
    }
    __builtin_amdgcn_s_barrier();
  }

  const int r0 = bm * 128 + wr * 64 + grp * 4;
  const int c0 = bn * 256 + wc * 64 + lrow;
#pragma unroll
  for (int n = 0; n < 4; ++n) {
    const int col = c0 + n * 16;
    const float bc = bsel[col];
#pragma unroll
    for (int qm = 0; qm < 4; ++qm)
#pragma unroll
      for (int j = 0; j < 4; ++j) {
        float v = acc[qm][n][j] + bc;
        if (RELU) v = fmaxf(v, 0.f);
        Yb[(size_t)(r0 + qm * 16 + j) * ldy + col] = f2b(v);
      }
  }
}

// ---------------- fused GEMM + bias + residual + LayerNorm (64x512 tile) ------
// Out = LN(A @ W^T + bias + Res). 512 thr, 8 waves each owning a 64-col slice;
// block owns 64 FULL rows -> LN stats computed locally (f32 throughout).
// 2 LDS buffers (A 8KB + W 64KB each), stage(g+1)-during-compute(g). (R11 ver.)
// OUT=0: bf16 out; OUT=1: f32 out (final layer).
template <int OUT>
__global__ __launch_bounds__(512) void gemm_ln(
    const bf16_t* __restrict__ A, const bf16_t* __restrict__ W,
    const float* __restrict__ bias, const bf16_t* __restrict__ Res,
    const float* __restrict__ gam, const float* __restrict__ bet,
    bf16_t* __restrict__ outb, float* __restrict__ outf) {
  const int K = 512;
  const int bm = blockIdx.x;
  const int tid = threadIdx.x, wid = tid >> 6, lane = tid & 63;
  const int lrow = lane & 15, grp = lane >> 4;
  const int l3 = lane >> 3, c3 = lane & 7;

  __shared__ __align__(16) bf16_t Lds[2][36864];  // per buf: A[64][64] | W[512][64]
  __shared__ float red_s[64][8], red_q[64][8], stat[64][2];

  f32x4 acc[4][4];
#pragma unroll
  for (int m = 0; m < 4; ++m)
#pragma unroll
    for (int n = 0; n < 4; ++n) acc[m][n] = f32x4{0.f, 0.f, 0.f, 0.f};

  const char* LB = (const char*)Lds;

  auto stage = [&](int kt, int buf) {
#pragma unroll
    for (int k = 0; k < 9; ++k) {
      const int c = wid + k * 8;           // 0..71
      const int colb = (c3 ^ l3) * 8;      // pre-swizzled 16B col
      if (c < 8) {                         // A chunk: rows c*8..c*8+7
        gload_lds16(A + (size_t)(bm * 64 + c * 8 + l3) * K + kt * 64 + colb,
                    &Lds[buf][c * 512]);
      } else {                             // W chunk
        const int cb = c - 8;
        gload_lds16(W + (size_t)(cb * 8 + l3) * K + kt * 64 + colb,
                    &Lds[buf][4096 + cb * 512]);
      }
    }
  };
  auto rdA = [&](int buf, int r, int ks) -> bf16x8 {
    const int off = buf * 73728 + r * 128 + ((ks * 64 + grp * 16) ^ ((r & 7) << 4));
    return *reinterpret_cast<const bf16x8*>(LB + off);
  };
  auto rdW = [&](int buf, int r, int ks) -> bf16x8 {
    const int off = buf * 73728 + 8192 + r * 128 + ((ks * 64 + grp * 16) ^ ((r & 7) << 4));
    return *reinterpret_cast<const bf16x8*>(LB + off);
  };

  stage(0, 0);
  __syncthreads();
  for (int g = 0; g < 8; ++g) {
    const int bufR = g & 1;
    if (g < 7) stage(g + 1, bufR ^ 1);
    bf16x8 af[4][2], wf[4][2];
#pragma unroll
    for (int m = 0; m < 4; ++m)
#pragma unroll
      for (int ks = 0; ks < 2; ++ks)
        af[m][ks] = rdA(bufR, m * 16 + lrow, ks);
#pragma unroll
    for (int n = 0; n < 4; ++n)
#pragma unroll
      for (int ks = 0; ks < 2; ++ks)
        wf[n][ks] = rdW(bufR, wid * 64 + n * 16 + lrow, ks);
    __builtin_amdgcn_s_setprio(1);
#pragma unroll
    for (int ks = 0; ks < 2; ++ks)
#pragma unroll
      for (int m = 0; m < 4; ++m)
#pragma unroll
        for (int n = 0; n < 4; ++n)
          acc[m][n] = __builtin_amdgcn_mfma_f32_16x16x32_bf16(af[m][ks], wf[n][ks], acc[m][n], 0, 0, 0);
    __builtin_amdgcn_s_setprio(0);
    __syncthreads();   // drains vmcnt (stage g+1 resident) + lgkm
  }

  // ---- epilogue: z = acc + bias + res; rowwise LN; store ----
  const int cbase = wid * 64;
  float bias_n[4], gam_n[4], bet_n[4];
#pragma unroll
  for (int n = 0; n < 4; ++n) {
    bias_n[n] = bias[cbase + n * 16 + lrow];
    gam_n[n]  = gam[cbase + n * 16 + lrow];
    bet_n[n]  = bet[cbase + n * 16 + lrow];
  }
  const size_t rowg0 = (size_t)bm * 64;
  float ps[4][4], pq[4][4];
#pragma unroll
  for (int m = 0; m < 4; ++m)
#pragma unroll
    for (int j = 0; j < 4; ++j) {
      const int r = m * 16 + grp * 4 + j;
      float s = 0.f, q = 0.f;
#pragma unroll
      for (int n = 0; n < 4; ++n) {
        float z = acc[m][n][j] + bias_n[n] +
                  bf2f(Res[(rowg0 + r) * DM + cbase + n * 16 + lrow]);
        acc[m][n][j] = z;
        s += z; q += z * z;
      }
      ps[m][j] = s; pq[m][j] = q;
    }
#pragma unroll
  for (int m = 0; m < 4; ++m)
#pragma unroll
    for (int j = 0; j < 4; ++j)
#pragma unroll
      for (int off = 1; off <= 8; off <<= 1) {
        ps[m][j] += __shfl_xor(ps[m][j], off);
        pq[m][j] += __shfl_xor(pq[m][j], off);
      }
  if (lrow == 0) {
#pragma unroll
    for (int m = 0; m < 4; ++m)
#pragma unroll
      for (int j = 0; j < 4; ++j) {
        const int r = m * 16 + grp * 4 + j;
        red_s[r][wid] = ps[m][j];
        red_q[r][wid] = pq[m][j];
      }
  }
  __syncthreads();
  if (tid < 64) {
    float s = 0.f, q = 0.f;
#pragma unroll
    for (int w = 0; w < 8; ++w) { s += red_s[tid][w]; q += red_q[tid][w]; }
    const float mean = s * (1.f / 512.f);
    const float var = q * (1.f / 512.f) - mean * mean;
    stat[tid][0] = mean;
    stat[tid][1] = rsqrtf(var + 1e-5f);
  }
  __syncthreads();
#pragma unroll
  for (int m = 0; m < 4; ++m)
#pragma unroll
    for (int j = 0; j < 4; ++j) {
      const int r = m * 16 + grp * 4 + j;
      const float mean = stat[r][0], rstd = stat[r][1];
#pragma unroll
      for (int n = 0; n < 4; ++n) {
        const float o = (acc[m][n][j] - mean) * rstd * gam_n[n] + bet_n[n];
        const size_t off = (rowg0 + r) * DM + cbase + n * 16 + lrow;
        if (OUT == 0) outb[off] = f2b(o);
        else outf[off] = o;
      }
    }
}

// ---------------- gating: softmax(q @ Wg^T), top-4-of-6, fused routing ----------------
__global__ __launch_bounds__(256) void gates_kernel(
    const bf16_t* __restrict__ qv, const float* __restrict__ Wg,
    float* __restrict__ rdyn, float* __restrict__ fP) {
  __shared__ float wg_s[HD_ * DM];
  __shared__ float blk[4][18];
  const int tid = threadIdx.x, wid = tid >> 6, lane = tid & 63;
  for (int i = tid; i < HD_ * DM / 4; i += 256)
    reinterpret_cast<float4*>(wg_s)[i] = reinterpret_cast<const float4*>(Wg)[i];
  __syncthreads();
  const int bb = blockIdx.x >> 4;
  const int t0 = (blockIdx.x & 15) * 32 + wid * 8;
  float fs[6] = {0, 0, 0, 0, 0, 0}, ps[6] = {0, 0, 0, 0, 0, 0}, rs[6] = {0, 0, 0, 0, 0, 0};
  for (int it = 0; it < 8; ++it) {
    const int tok = bb * SEQ + t0 + it;
    uint4 u = reinterpret_cast<const uint4*>(qv + (size_t)tok * QVLD)[lane];
    float x[8];
    unp2(u.x, x[0], x[1]); unp2(u.y, x[2], x[3]);
    unp2(u.z, x[4], x[5]); unp2(u.w, x[6], x[7]);
    float g[6];
#pragma unroll
    for (int j = 0; j < 6; ++j) {
      float p = 0.f;
#pragma unroll
      for (int e = 0; e < 8; ++e) p = fmaf(x[e], wg_s[j * DM + lane * 8 + e], p);
#pragma unroll
      for (int off = 32; off; off >>= 1) p += __shfl_xor(p, off);
      g[j] = p;
    }
    float mx = g[0];
#pragma unroll
    for (int j = 1; j < 6; ++j) mx = fmaxf(mx, g[j]);
    float se = 0.f;
#pragma unroll
    for (int j = 0; j < 6; ++j) { g[j] = __expf(g[j] - mx); se += g[j]; }
    float inv = 1.f / se;
#pragma unroll
    for (int j = 0; j < 6; ++j) g[j] *= inv;
    int d1 = 0;
#pragma unroll
    for (int j = 1; j < 6; ++j)
      if (g[j] < g[d1] || (g[j] == g[d1] && j > d1)) d1 = j;
    int d2 = (d1 == 0) ? 1 : 0;
#pragma unroll
    for (int j = 0; j < 6; ++j) {
      if (j == d1) continue;
      if (g[j] < g[d2] || (g[j] == g[d2] && j > d2)) d2 = j;
    }
#pragma unroll
    for (int j = 0; j < 6; ++j) {
      const bool drop = (j == d1) || (j == d2);
      fs[j] += drop ? 0.f : 1.f;
      ps[j] += g[j];
      rs[j] += drop ? 0.f : g[j];
    }
  }
  if (lane == 0) {
#pragma unroll
    for (int j = 0; j < 6; ++j) {
      blk[wid][j] = fs[j]; blk[wid][6 + j] = ps[j]; blk[wid][12 + j] = rs[j];
    }
  }
  __syncthreads();
  if (tid < 18) {
    float s = blk[0][tid] + blk[1][tid] + blk[2][tid] + blk[3][tid];
    if (tid < 12) atomicAdd(&fP[tid], s);
    else atomicAdd(&rdyn[bb * 6 + (tid - 12)], s * (1.f / 512.f));
  }
}

// ---------------- fused flash attention (MFMA, row0 fused, occupancy grid) ----
__global__ __launch_bounds__(256, 2) void fattn_kernel(
    const bf16_t* __restrict__ qv, const float* __restrict__ rdyn,
    bf16_t* __restrict__ ctx, int strict) {
  const int bh = blockIdx.x, qt = blockIdx.y;
  const int b = bh >> 3, h = bh & 7;
  const int tid = threadIdx.x, wid = tid >> 6, lane = tid & 63;
  const int c0 = lane & 15, grp = lane >> 4;
  const int l3 = lane >> 3, c3 = lane & 7;
  const int kidx = lane & 31, dhalf = lane >> 5;

  __shared__ __align__(16) bf16_t Ks[64 * 64];
  __shared__ __align__(16) bf16_t Vt[64 * 72];
  __shared__ __align__(16) bf16_t Ps[4][32 * 64];
  __shared__ float csum[64];

  const bf16_t* qp = qv;
  const bf16_t* vp = qv + 512;
  const float factor = (h < HS_) ? 1.f : rdyn[b * 6 + (h - HS_)];

  const int qbase = qt * 128 + wid * 32;

  bf16x8 qf[2][2];
#pragma unroll
  for (int nt = 0; nt < 2; ++nt)
#pragma unroll
    for (int ks = 0; ks < 2; ++ks)
      qf[nt][ks] = scale_q(*reinterpret_cast<const bf16x8*>(
          qp + ((size_t)(b * SEQ + qbase + nt * 16 + c0)) * QVLD + h * DK + ks * 32 + grp * 8));

  f32x4 acc[2][4];
#pragma unroll
  for (int m = 0; m < 2; ++m)
#pragma unroll
    for (int d = 0; d < 4; ++d) acc[m][d] = f32x4{0.f, 0.f, 0.f, 0.f};
  float mreg[2] = {-3e38f, -3e38f};
  float lreg[2] = {0.f, 0.f};
  float cs[8] = {0, 0, 0, 0, 0, 0, 0, 0};

  const int lastk = (qbase + 31 - strict) >> 6;
  const int ktmax = 2 * qt + 1;

  for (int kt = 0; kt <= ktmax; ++kt) {
#pragma unroll
    for (int i = 0; i < 2; ++i) {
      int row = i * 32 + wid * 8 + l3;
      int blk = c3 ^ l3;
      gload_lds16(qp + ((size_t)(b * SEQ + kt * 64 + row)) * QVLD + h * DK + blk * 8,
                  Ks + (i * 32 + wid * 8) * 64);
    }
#pragma unroll
    for (int j = 0; j < 2; ++j) {
      const int d0 = (wid * 2 + j) * 8 + dhalf * 4;
      const bf16_t* src = vp + ((size_t)(b * SEQ + kt * 64 + 2 * kidx)) * QVLD + h * DK + d0;
      ushort4 lo = *reinterpret_cast<const ushort4*>(src);
      ushort4 hv = *reinterpret_cast<const ushort4*>(src + QVLD);
      *reinterpret_cast<unsigned*>(&Vt[(d0 + 0) * 72 + 2 * kidx]) = (unsigned)lo.x | ((unsigned)hv.x << 16);
      *reinterpret_cast<unsigned*>(&Vt[(d0 + 1) * 72 + 2 * kidx]) = (unsigned)lo.y | ((unsigned)hv.y << 16);
      *reinterpret_cast<unsigned*>(&Vt[(d0 + 2) * 72 + 2 * kidx]) = (unsigned)lo.z | ((unsigned)hv.z << 16);
      *reinterpret_cast<unsigned*>(&Vt[(d0 + 3) * 72 + 2 * kidx]) = (unsigned)lo.w | ((unsigned)hv.w << 16);
      if (qt == 3) {
        cs[j * 4 + 0] += bf2f(lo.x) + bf2f(hv.x);
        cs[j * 4 + 1] += bf2f(lo.y) + bf2f(hv.y);
        cs[j * 4 + 2] += bf2f(lo.z) + bf2f(hv.z);
        cs[j * 4 + 3] += bf2f(lo.w) + bf2f(hv.w);
      }
    }
    __syncthreads();

    if (kt <= lastk) {
      const char* KsB = (const char*)Ks;
      bf16x8 kf[4][2];
#pragma unroll
      for (int mt = 0; mt < 4; ++mt)
#pragma unroll
        for (int ks = 0; ks < 2; ++ks)
          kf[mt][ks] = *reinterpret_cast<const bf16x8*>(
              KsB + (mt * 16 + c0) * 128 + 16 * ((4 * ks + grp) ^ (c0 & 7)));
      f32x4 s[4][2];
#pragma unroll
      for (int mt = 0; mt < 4; ++mt)
#pragma unroll
        for (int nt = 0; nt < 2; ++nt) s[mt][nt] = f32x4{0.f, 0.f, 0.f, 0.f};
      __builtin_amdgcn_s_setprio(1);
#pragma unroll
      for (int mt = 0; mt < 4; ++mt)
#pragma unroll
        for (int nt = 0; nt < 2; ++nt)
#pragma unroll
          for (int ks = 0; ks < 2; ++ks)
            s[mt][nt] = __builtin_amdgcn_mfma_f32_16x16x32_bf16(
                kf[mt][ks], qf[nt][ks], s[mt][nt], 0, 0, 0);
      __builtin_amdgcn_s_setprio(0);

      const bool masked = (kt == lastk);
      if (masked) {
#pragma unroll
        for (int nt = 0; nt < 2; ++nt) {
          const int q = qbase + nt * 16 + c0;
#pragma unroll
          for (int mt = 0; mt < 4; ++mt)
#pragma unroll
            for (int j = 0; j < 4; ++j) {
              int k = kt * 64 + mt * 16 + grp * 4 + j;
              if (k + strict > q) s[mt][nt][j] = -1e30f;
            }
        }
      }
      float mx[2];
#pragma unroll
      for (int nt = 0; nt < 2; ++nt) {
        float a = fmaxf(s[0][nt][0], s[0][nt][1]);
        a = fmaxf(fmaxf(a, s[0][nt][2]), s[0][nt][3]);
        float bm_ = fmaxf(s[1][nt][0], s[1][nt][1]);
        bm_ = fmaxf(fmaxf(bm_, s[1][nt][2]), s[1][nt][3]);
        float c = fmaxf(s[2][nt][0], s[2][nt][1]);
        c = fmaxf(fmaxf(c, s[2][nt][2]), s[2][nt][3]);
        float d = fmaxf(s[3][nt][0], s[3][nt][1]);
        d = fmaxf(fmaxf(d, s[3][nt][2]), s[3][nt][3]);
        float m_ = fmaxf(fmaxf(a, bm_), fmaxf(c, d));
        m_ = fmaxf(m_, __shfl_xor(m_, 16));
        m_ = fmaxf(m_, __shfl_xor(m_, 32));
        mx[nt] = m_;
      }
      const bool defer = __all((mx[0] - mreg[0] <= 8.f) && (mx[1] - mreg[1] <= 8.f));
      float sc[2];
#pragma unroll
      for (int nt = 0; nt < 2; ++nt) {
        const float mnew = defer ? mreg[nt] : fmaxf(mreg[nt], mx[nt]);
        float ts = 0.f;
#pragma unroll
        for (int mt = 0; mt < 4; ++mt)
#pragma unroll
          for (int j = 0; j < 4; ++j) {
            float pp = exp2f(s[mt][nt][j] - mnew);
            s[mt][nt][j] = pp; ts += pp;
          }
        ts += __shfl_xor(ts, 16);
        ts += __shfl_xor(ts, 32);
        if (defer) {
          lreg[nt] += ts;
        } else {
          sc[nt] = exp2f(mreg[nt] - mnew);
          lreg[nt] = lreg[nt] * sc[nt] + ts;
          mreg[nt] = mnew;
        }
      }
      char* PsB = (char*)(&Ps[wid][0]);
#pragma unroll
      for (int nt = 0; nt < 2; ++nt)
#pragma unroll
        for (int mt = 0; mt < 4; ++mt) {
          uint2 w;
          w.x = cvtpk(s[mt][nt][0], s[mt][nt][1]);
          w.y = cvtpk(s[mt][nt][2], s[mt][nt][3]);
          int row = nt * 16 + c0;
          int off = (row * 128 + mt * 32 + grp * 8) ^ ((c0 & 7) << 4);
          *reinterpret_cast<uint2*>(PsB + off) = w;
        }
      if (!defer) {
#pragma unroll
        for (int mtq = 0; mtq < 2; ++mtq) {
          f32x4 sv;
#pragma unroll
          for (int j = 0; j < 4; ++j) sv[j] = __shfl(sc[mtq], grp * 4 + j);
#pragma unroll
          for (int dt = 0; dt < 4; ++dt) acc[mtq][dt] *= sv;
        }
      }
      bf16x8 pf[2][2], vf2[4][2];
#pragma unroll
      for (int mtq = 0; mtq < 2; ++mtq)
#pragma unroll
        for (int ks = 0; ks < 2; ++ks)
          pf[mtq][ks] = *reinterpret_cast<const bf16x8*>(
              PsB + (mtq * 16 + c0) * 128 + 16 * ((4 * ks + grp) ^ (c0 & 7)));
#pragma unroll
      for (int dt = 0; dt < 4; ++dt)
#pragma unroll
        for (int ks = 0; ks < 2; ++ks)
          vf2[dt][ks] = *reinterpret_cast<const bf16x8*>(
              (const char*)Vt + (dt * 16 + c0) * 144 + ks * 64 + grp * 16);
      __builtin_amdgcn_s_setprio(1);
#pragma unroll
      for (int mtq = 0; mtq < 2; ++mtq)
#pragma unroll
        for (int dt = 0; dt < 4; ++dt)
#pragma unroll
          for (int ks = 0; ks < 2; ++ks)
            acc[mtq][dt] = __builtin_amdgcn_mfma_f32_16x16x32_bf16(
                pf[mtq][ks], vf2[dt][ks], acc[mtq][dt], 0, 0, 0);
      __builtin_amdgcn_s_setprio(0);
    }
    __syncthreads();
  }

  if (qt == 3) {
#pragma unroll
    for (int e = 0; e < 8; ++e)
#pragma unroll
      for (int off = 1; off <= 16; off <<= 1) cs[e] += __shfl_xor(cs[e], off);
    if ((lane & 31) == 0) {
#pragma unroll
      for (int e = 0; e < 8; ++e)
        csum[(wid * 2 + (e >> 2)) * 8 + dhalf * 4 + (e & 3)] = cs[e];
    }
    __syncthreads();
    if (tid < 64)
      ctx[((size_t)(b * SEQ)) * DM + h * DK + tid] = f2b(csum[tid] * (1.f / 512.f) * factor);
  }

#pragma unroll
  for (int mtq = 0; mtq < 2; ++mtq) {
    const float inv = factor / lreg[mtq];
    f32x4 iv;
#pragma unroll
    for (int j = 0; j < 4; ++j) iv[j] = __shfl(inv, grp * 4 + j);
#pragma unroll
    for (int j = 0; j < 4; ++j) {
      const int q = qbase + mtq * 16 + grp * 4 + j;
      if (q == 0) continue;
#pragma unroll
      for (int dt = 0; dt < 4; ++dt)
        ctx[((size_t)(b * SEQ + q)) * DM + h * DK + dt * 16 + c0] =
            f2b(acc[mtq][dt][j] * iv[j]);
    }
  }
}

// ---------------- balance ----------------
__global__ void balance_kernel(const float* __restrict__ fP, float* __restrict__ out) {
  if (threadIdx.x == 0 && blockIdx.x == 0) {
    float fs = 0.f, pssum = 0.f, P[6];
    for (int j = 0; j < 6; ++j) {
      fs += fP[j];
      P[j] = fP[6 + j] * (1.f / (float)MROWS);
      pssum += P[j];
    }
    float bal = 0.f;
    for (int j = 0; j < 6; ++j)
      bal += (fP[j] / (fs + 1e-5f)) * (P[j] / (pssum + 1e-5f));
    out[0] = bal;
  }
}

// ---------------- host ----------------
extern "C" void kernel_launch(void* const* d_in, const int* in_sizes, int n_in,
                              void* d_out, int out_size, void* d_ws, size_t ws_size,
                              hipStream_t stream) {
  (void)in_sizes; (void)n_in; (void)out_size; (void)ws_size;
  const float* q_embed  = (const float*)d_in[0];
  const float* qa_embed = (const float*)d_in[1];
  const float* Wq  = (const float*)d_in[2];
  const float* bq  = (const float*)d_in[3];
  const float* Wv  = (const float*)d_in[4];
  const float* bv  = (const float*)d_in[5];
  const float* Wg  = (const float*)d_in[6];
  const float* Wo  = (const float*)d_in[7];
  const float* bo  = (const float*)d_in[8];
  const float* ln1g = (const float*)d_in[9];
  const float* ln1b = (const float*)d_in[10];
  const float* W1  = (const float*)d_in[11];
  const float* b1  = (const float*)d_in[12];
  const float* W2  = (const float*)d_in[13];
  const float* b2  = (const float*)d_in[14];
  const float* ln2g = (const float*)d_in[15];
  const float* ln2b = (const float*)d_in[16];

  char* p = (char*)d_ws;
  auto alloc = [&](size_t bytes) -> char* {
    char* r = p; p += (bytes + 255) & ~(size_t)255; return r;
  };
  const size_t WDE = (size_t)NL * DM * DM;   // stacked weight elems (per tensor)
  const size_t AE  = (size_t)MROWS * DM;     // activation elems
  bf16_t* wall_b = (bf16_t*)alloc(5 * WDE * 2);   // wq|wv|wo|w1|w2 contiguous
  bf16_t* wq_b = wall_b;
  bf16_t* wv_b = wall_b + WDE;
  bf16_t* wo_b = wall_b + 2 * WDE;
  bf16_t* w1_b = wall_b + 3 * WDE;
  bf16_t* w2_b = wall_b + 4 * WDE;
  bf16_t* y_b   = (bf16_t*)alloc(AE * 2);
  bf16_t* x_b   = (bf16_t*)alloc(AE * 2);
  bf16_t* qv_b  = (bf16_t*)alloc((size_t)MROWS * QVLD * 2);  // q|v merged
  bf16_t* ctx_b = (bf16_t*)alloc(AE * 2);
  bf16_t* x1_b  = (bf16_t*)alloc(AE * 2);
  bf16_t* ffn1_b = (bf16_t*)alloc(AE * 2);
  float* stats = (float*)alloc(NL * (12 + BSZ * 6) * 4);  // fP[NL][12] | rdyn[NL][32][6]
  float* fPbase = stats;
  float* rdynbase = stats + NL * 12;

  hipMemsetAsync(stats, 0, NL * (12 + BSZ * 6) * 4, stream);

  f2bw_kernel<<<dim3((unsigned)(WDE / 4 / 256), 5), 256, 0, stream>>>(
      Wq, Wv, Wo, W1, W2, wall_b);
  f2b2_kernel<<<dim3((unsigned)(AE / 4 / 256), 2), 256, 0, stream>>>(
      qa_embed, q_embed, y_b, x_b);

  const size_t DD = (size_t)DM * DM;
  dim3 gqv(4, 128), gn5(2, 128), gfa(256, 4), gln(256);
  float* outx = (float*)d_out;

  auto layer = [&](int i, bf16_t* resb, const bf16_t* xvb, int strict, bool last) {
    float* fP = fPbase + i * 12;
    float* rdyn = rdynbase + i * (BSZ * 6);
    gemm8<4, 512, false><<<gqv, 512, 0, stream>>>(
        resb, xvb, wq_b + i * DD, wv_b + i * DD, bq + i * DM, bv + i * DM, qv_b, QVLD);
    gates_kernel<<<MROWS / 32, 256, 0, stream>>>(qv_b, Wg + (size_t)i * HD_ * DM, rdyn, fP);
    fattn_kernel<<<gfa, 256, 0, stream>>>(qv_b, rdyn, ctx_b, strict);
    // attn-out projection + residual + LN1 fused
    gemm_ln<0><<<gln, 512, 0, stream>>>(
        ctx_b, wo_b + i * DD, bo + i * DM, resb, ln1g + i * DM, ln1b + i * DM,
        x1_b, nullptr);
    gemm8<2, 256, true><<<gn5, 512, 0, stream>>>(
        x1_b, x1_b, w1_b + i * DD, w1_b + i * DD, b1 + i * DM, b1 + i * DM, ffn1_b, DM);
    // FFN2 + residual + LN2 fused
    if (last)
      gemm_ln<1><<<gln, 512, 0, stream>>>(
          ffn1_b, w2_b + i * DD, b2 + i * DM, x1_b, ln2g + i * DM, ln2b + i * DM,
          nullptr, outx);
    else
      gemm_ln<0><<<gln, 512, 0, stream>>>(
          ffn1_b, w2_b + i * DD, b2 + i * DM, x1_b, ln2g + i * DM, ln2b + i * DM,
          resb, nullptr);
  };

  layer(0, y_b, y_b, 0, false);
  layer(1, y_b, y_b, 0, false);
  layer(2, x_b, x_b, 0, false);
  layer(3, x_b, y_b, 1, false);
  layer(4, x_b, x_b, 0, false);
  layer(5, x_b, y_b, 1, true);
  balance_kernel<<<1, 64, 0, stream>>>(fPbase + 5 * 12, outx + (size_t)MROWS * DM);
}